// Round 7
// baseline (260.860 us; speedup 1.0000x reference)
//
#include <hip/hip_runtime.h>
#include <math.h>

// BinaryTreeLSTM on MI355X — R10.
// vs R9 (227us): fuse levels B=512..1 (10 levels) into ONE kernel with lean
// producer-count flag barriers (release atomicAdd + relaxed poll + acquire),
// NOT cg::grid.sync (R4: 9us/sync). 128 blocks (8 row-pairs x 16 grps),
// 80KB grp weight slice staged in LDS once, reused across all 10 levels.
// Co-residency: 80KB LDS => <=2 blocks/CU, 128 <= 256 CUs -> no deadlock.
// Flags zeroed by prep1 each iteration (graph-replay safe).
// Dispatches: prep1, leaf_fused, rt2(4096), ksplit(2048), ksplit(1024),
// tail(512..1) = 6 (was 15; ~4us gap each).

#define MEM 256

typedef __attribute__((ext_vector_type(8))) short bf16x8;
typedef __attribute__((ext_vector_type(4))) float f32x4;

__device__ __forceinline__ float sigf(float x) { return 1.0f / (1.0f + __expf(-x)); }

__device__ __forceinline__ unsigned short f2b(float f) {
  unsigned int u = __float_as_uint(f);
  u = (u + 0x7FFFu + ((u >> 16) & 1u)) >> 16;
  return (unsigned short)u;
}

// 8 consecutive f32 -> bf16x8
__device__ __forceinline__ bf16x8 c8(const float* __restrict__ p) {
  float4 f0 = *(const float4*)(p);
  float4 f1 = *(const float4*)(p + 4);
  bf16x8 r;
  r[0] = (short)f2b(f0.x); r[1] = (short)f2b(f0.y);
  r[2] = (short)f2b(f0.z); r[3] = (short)f2b(f0.w);
  r[4] = (short)f2b(f1.x); r[5] = (short)f2b(f1.y);
  r[6] = (short)f2b(f1.z); r[7] = (short)f2b(f1.w);
  return r;
}

// 8 consecutive k from a 300-long f32 row, zero-padded past 300
__device__ __forceinline__ bf16x8 g8(const float* __restrict__ rp, int k0) {
  if (k0 + 8 <= 300) return c8(rp + k0);
  bf16x8 r;
#pragma unroll
  for (int j = 0; j < 8; j++) {
    int k = k0 + j;
    r[j] = (k < 300) ? (short)f2b(rp[k]) : (short)0;
  }
  return r;
}

// ---- Prep1: eb (embs->bf16) | Wxf shuffle | zero tail flags ----
#define NB_EB 1280   // 8192*320/2048
#define NB_WXF 120   // 480*512/2048
__global__ __launch_bounds__(256) void k_prep1(
    const float* __restrict__ embs, const float* __restrict__ Wx,
    unsigned short* __restrict__ eb, unsigned short* __restrict__ Wxf,
    unsigned int* __restrict__ flags) {
  int b = blockIdx.x, tid = threadIdx.x;
  if (b == 0 && tid < 16) flags[tid] = 0u;  // kernel-end implicit release
  if (b < NB_EB) {
    int idx8 = (b * 256 + tid) * 8;       // 8192*320
    int row = idx8 / 320;
    int k0 = idx8 - row * 320;
    *(bf16x8*)(eb + idx8) = g8(embs + row * 300, k0);
  } else {
    int idx8 = ((b - NB_EB) * 256 + tid) * 8;  // 480*512
    int f = idx8 >> 9, rr = idx8 & 511;
    int lane = rr >> 3;
    int gate = f % 3, t = f / 3;
    int grp = t & 15, kc = t >> 4;
    int k0 = kc * 32 + ((lane >> 4) << 3);
    const int gmap[3] = {0, 1, 3};
    int n = gmap[gate] * 256 + (grp << 4) + (lane & 15);
    *(bf16x8*)(Wxf + idx8) = g8(Wx + n * 300, k0);
  }
}

// ---- Leaf (0..1023) | Wcf shuffle (1024..1343) | bias5 (1344..1348) ----
#define NB_LEAF 1024
#define NB_WCF 320   // 1280*512/2048
__global__ __launch_bounds__(256) void k_leaf_fused(
    const unsigned short* __restrict__ eb, const unsigned short* __restrict__ Wxf,
    const float* __restrict__ bx, const float* __restrict__ Wx,
    const float* __restrict__ Wl, const float* __restrict__ Wr,
    const float* __restrict__ emb_last,
    unsigned short* __restrict__ Wcf, float* __restrict__ bias5,
    float* __restrict__ cO, unsigned short* __restrict__ hO) {
  int b = blockIdx.x, tid = threadIdx.x;
  if (b < NB_LEAF) {
    int slice = b & 7, rest = b >> 3;
    int rowblock = slice * 8 + (rest & 7);
    int grp = rest >> 3;
    int lane = tid & 63, wave = tid >> 6;
    int tb = (rowblock * 4 + wave) * 2;
    int m = lane & 15, quad = lane >> 4;

    f32x4 acc[2][3];
#pragma unroll
    for (int rt = 0; rt < 2; rt++)
#pragma unroll
      for (int g = 0; g < 3; g++) acc[rt][g] = (f32x4){0.f, 0.f, 0.f, 0.f};

    const unsigned short* ar0 = eb + (tb * 16 + m) * 320 + quad * 8;
    const unsigned short* ar1 = eb + ((tb + 1) * 16 + m) * 320 + quad * 8;
#pragma unroll
    for (int kc = 0; kc < 10; kc++) {
      const unsigned short* bp = Wxf + ((kc * 16 + grp) * 3) * 512 + lane * 8;
      bf16x8 b0 = *(const bf16x8*)(bp);
      bf16x8 b1 = *(const bf16x8*)(bp + 512);
      bf16x8 b2 = *(const bf16x8*)(bp + 1024);
      bf16x8 a0 = *(const bf16x8*)(ar0 + kc * 32);
      bf16x8 a1 = *(const bf16x8*)(ar1 + kc * 32);
      acc[0][0] = __builtin_amdgcn_mfma_f32_16x16x32_bf16(a0, b0, acc[0][0], 0, 0, 0);
      acc[0][1] = __builtin_amdgcn_mfma_f32_16x16x32_bf16(a0, b1, acc[0][1], 0, 0, 0);
      acc[0][2] = __builtin_amdgcn_mfma_f32_16x16x32_bf16(a0, b2, acc[0][2], 0, 0, 0);
      acc[1][0] = __builtin_amdgcn_mfma_f32_16x16x32_bf16(a1, b0, acc[1][0], 0, 0, 0);
      acc[1][1] = __builtin_amdgcn_mfma_f32_16x16x32_bf16(a1, b1, acc[1][1], 0, 0, 0);
      acc[1][2] = __builtin_amdgcn_mfma_f32_16x16x32_bf16(a1, b2, acc[1][2], 0, 0, 0);
    }
    int col = grp * 16 + m;
    float b0 = bx[col], b1 = bx[256 + col], b3 = bx[768 + col];
#pragma unroll
    for (int rt = 0; rt < 2; rt++) {
#pragma unroll
      for (int reg = 0; reg < 4; reg++) {
        int row = (tb + rt) * 16 + quad * 4 + reg;
        float u = tanhf(acc[rt][0][reg] + b0);
        float ig = sigf(acc[rt][1][reg] + b1);
        float o = sigf(acc[rt][2][reg] + b3);
        float c = ig * u;
        cO[row * MEM + col] = c;
        hO[row * MEM + col] = f2b(o * tanhf(c));
      }
    }
  } else if (b < NB_LEAF + NB_WCF) {
    int idx8 = ((b - NB_LEAF) * 256 + tid) * 8;  // 1280*512
    int f = idx8 >> 9, rr = idx8 & 511;
    int lane = rr >> 3;
    int gate = f % 5, t = f / 5;
    int grp = t & 15, kc = t >> 4;
    int k0 = kc * 32 + ((lane >> 4) << 3);
    int n = gate * 256 + (grp << 4) + (lane & 15);
    const float* src = (k0 < 256) ? (Wl + n * 256 + k0) : (Wr + n * 256 + (k0 - 256));
    *(bf16x8*)(Wcf + idx8) = c8(src);
  } else {
    int g = b - (NB_LEAF + NB_WCF);  // 0..4
    __shared__ float er[300];
    for (int k = tid; k < 300; k += 256) er[k] = emb_last[k];
    __syncthreads();
    const int map[5] = {0, 1, 2, 2, 3};
    int wrow = map[g] * 256 + tid;
    const float* w = Wx + wrow * 300;
    float s = bx[wrow];
    for (int k = 0; k < 300; k++) s += er[k] * w[k];
    bias5[g * 256 + tid] = s;
  }
}

// ---- Compose RT=2 (B=4096 only): 1-D grid(512), row-affine slices ----
__global__ __launch_bounds__(256) void k_compose_rt2(
    const unsigned short* __restrict__ hprev, const float* __restrict__ cprev,
    const unsigned short* __restrict__ Wcf, const float* __restrict__ bias5,
    float* __restrict__ cO, unsigned short* __restrict__ hO, int B) {
  int bid = blockIdx.x;
  int slice = bid & 7;
  int rest = bid >> 3;
  int rowblock = slice * 4 + (rest & 3);
  int grp = rest >> 2;
  int lane = threadIdx.x & 63;
  int wave = threadIdx.x >> 6;
  int tb = (rowblock * 4 + wave) * 2;
  int m = lane & 15, quad = lane >> 4;

  f32x4 acc[2][5];
  const unsigned short* ar[2];
#pragma unroll
  for (int rt = 0; rt < 2; rt++) {
    int ra = (tb + rt) * 16 + m;
    ar[rt] = hprev + ra * 512 + quad * 8;
#pragma unroll
    for (int g = 0; g < 5; g++) acc[rt][g] = (f32x4){0.f, 0.f, 0.f, 0.f};
  }

#pragma unroll
  for (int kc = 0; kc < 16; kc++) {
    const unsigned short* bp = Wcf + ((kc * 16 + grp) * 5) * 512 + lane * 8;
    bf16x8 b0 = *(const bf16x8*)(bp);
    bf16x8 b1 = *(const bf16x8*)(bp + 512);
    bf16x8 b2 = *(const bf16x8*)(bp + 1024);
    bf16x8 b3 = *(const bf16x8*)(bp + 1536);
    bf16x8 b4 = *(const bf16x8*)(bp + 2048);
#pragma unroll
    for (int rt = 0; rt < 2; rt++) {
      bf16x8 a = *(const bf16x8*)(ar[rt] + kc * 32);
      acc[rt][0] = __builtin_amdgcn_mfma_f32_16x16x32_bf16(a, b0, acc[rt][0], 0, 0, 0);
      acc[rt][1] = __builtin_amdgcn_mfma_f32_16x16x32_bf16(a, b1, acc[rt][1], 0, 0, 0);
      acc[rt][2] = __builtin_amdgcn_mfma_f32_16x16x32_bf16(a, b2, acc[rt][2], 0, 0, 0);
      acc[rt][3] = __builtin_amdgcn_mfma_f32_16x16x32_bf16(a, b3, acc[rt][3], 0, 0, 0);
      acc[rt][4] = __builtin_amdgcn_mfma_f32_16x16x32_bf16(a, b4, acc[rt][4], 0, 0, 0);
    }
  }
  int col = grp * 16 + m;
  float b0 = bias5[col], b1 = bias5[256 + col], b2 = bias5[512 + col];
  float b3 = bias5[768 + col], b4 = bias5[1024 + col];
#pragma unroll
  for (int rt = 0; rt < 2; rt++) {
#pragma unroll
    for (int reg = 0; reg < 4; reg++) {
      int row = (tb + rt) * 16 + quad * 4 + reg;
      float u = tanhf(acc[rt][0][reg] + b0);
      float ig = sigf(acc[rt][1][reg] + b1);
      float lf = sigf(acc[rt][2][reg] + b2);
      float rf = sigf(acc[rt][3][reg] + b3);
      float o = sigf(acc[rt][4][reg] + b4);
      float lc = cprev[(2 * row) * MEM + col];
      float rc = cprev[(2 * row + 1) * MEM + col];
      float c = ig * u + lf * lc + rf * rc;
      cO[row * MEM + col] = c;
      hO[row * MEM + col] = f2b(o * tanhf(c));
    }
  }
}

// ---- K-split compose (B=2048,1024): grid(tiles/2,16) ----
__global__ __launch_bounds__(256, 4) void k_compose_ksplit(
    const unsigned short* __restrict__ hprev, const float* __restrict__ cprev,
    const unsigned short* __restrict__ Wcf, const float* __restrict__ bias5,
    float* __restrict__ cO, unsigned short* __restrict__ hO, int B) {
  __shared__ __align__(16) float lds[4 * 2 * 5 * 64 * 4];  // 40KB
  int tid = threadIdx.x;
  int lane = tid & 63, wave = tid >> 6;
  int grp = blockIdx.y;
  int tp = blockIdx.x;
  int m = lane & 15, quad = lane >> 4;

  f32x4 acc[2][5];
  bf16x8 av[2][4];
#pragma unroll
  for (int t = 0; t < 2; t++) {
    int ra = (2 * tp + t) * 16 + m;
    const unsigned short* ar = hprev + ra * 512 + quad * 8;
#pragma unroll
    for (int kcl = 0; kcl < 4; kcl++)
      av[t][kcl] = *(const bf16x8*)(ar + (wave * 4 + kcl) * 32);
#pragma unroll
    for (int q = 0; q < 5; q++) acc[t][q] = (f32x4){0.f, 0.f, 0.f, 0.f};
  }

#pragma unroll
  for (int kcl = 0; kcl < 4; kcl++) {
    int kc = wave * 4 + kcl;
    const unsigned short* bp = Wcf + ((kc * 16 + grp) * 5) * 512 + lane * 8;
    bf16x8 b0 = *(const bf16x8*)(bp);
    bf16x8 b1 = *(const bf16x8*)(bp + 512);
    bf16x8 b2 = *(const bf16x8*)(bp + 1024);
    bf16x8 b3 = *(const bf16x8*)(bp + 1536);
    bf16x8 b4 = *(const bf16x8*)(bp + 2048);
#pragma unroll
    for (int t = 0; t < 2; t++) {
      acc[t][0] = __builtin_amdgcn_mfma_f32_16x16x32_bf16(av[t][kcl], b0, acc[t][0], 0, 0, 0);
      acc[t][1] = __builtin_amdgcn_mfma_f32_16x16x32_bf16(av[t][kcl], b1, acc[t][1], 0, 0, 0);
      acc[t][2] = __builtin_amdgcn_mfma_f32_16x16x32_bf16(av[t][kcl], b2, acc[t][2], 0, 0, 0);
      acc[t][3] = __builtin_amdgcn_mfma_f32_16x16x32_bf16(av[t][kcl], b3, acc[t][3], 0, 0, 0);
      acc[t][4] = __builtin_amdgcn_mfma_f32_16x16x32_bf16(av[t][kcl], b4, acc[t][4], 0, 0, 0);
    }
  }
#pragma unroll
  for (int t = 0; t < 2; t++)
#pragma unroll
    for (int q = 0; q < 5; q++)
      *(f32x4*)&lds[(((wave * 2 + t) * 5 + q) * 64 + lane) * 4] = acc[t][q];
  __syncthreads();

  if (wave < 2) {
    int t = wave;
    int gt = 2 * tp + t;
    int col = grp * 16 + m;
    float b0 = bias5[col], b1 = bias5[256 + col], b2 = bias5[512 + col];
    float b3 = bias5[768 + col], b4 = bias5[1024 + col];
    f32x4 s[5];
#pragma unroll
    for (int q = 0; q < 5; q++) {
      s[q] = *(const f32x4*)&lds[(((0 * 2 + t) * 5 + q) * 64 + lane) * 4];
#pragma unroll
      for (int v = 1; v < 4; v++) {
        f32x4 p = *(const f32x4*)&lds[(((v * 2 + t) * 5 + q) * 64 + lane) * 4];
        s[q][0] += p[0]; s[q][1] += p[1]; s[q][2] += p[2]; s[q][3] += p[3];
      }
    }
#pragma unroll
    for (int reg = 0; reg < 4; reg++) {
      int row = gt * 16 + quad * 4 + reg;
      float u = tanhf(s[0][reg] + b0);
      float ig = sigf(s[1][reg] + b1);
      float lf = sigf(s[2][reg] + b2);
      float rf = sigf(s[3][reg] + b3);
      float o = sigf(s[4][reg] + b4);
      float lc = cprev[(2 * row) * MEM + col];
      float rc = cprev[(2 * row + 1) * MEM + col];
      float c = ig * u + lf * lc + rf * rc;
      cO[row * MEM + col] = c;
      hO[row * MEM + col] = f2b(o * tanhf(c));
    }
  }
}

// ---- Fused tail: levels B=512..1 in ONE kernel, lean flag barriers ----
// 128 blocks = 8 row-pairs (rp) x 16 grps (g). 80KB grp weight slice in LDS.
// Per level: wave w of rp handles tile t = rp*4+w. Barrier: release atomicAdd
// by producer blocks; all poll until count == 16*active_rps; acquire.
__global__ __launch_bounds__(256) void k_tail(
    const float* __restrict__ cs0, const unsigned short* __restrict__ hs0,
    float* __restrict__ cP0, unsigned short* __restrict__ hP0,
    float* __restrict__ cP1, unsigned short* __restrict__ hP1,
    const unsigned short* __restrict__ Wcf, const float* __restrict__ bias5,
    float* __restrict__ outv, unsigned int* __restrict__ flags) {
  __shared__ unsigned short wl[40960];  // 80KB: [kc*5+gate][512]
  int bid = blockIdx.x;
  int g = bid & 15, rp = bid >> 4;  // g 0..15, rp 0..7
  int tid = threadIdx.x;
#pragma unroll
  for (int j = 0; j < 20; j++) {
    int off8 = (j * 256 + tid) * 8;
    int i = off8 >> 9, inner = off8 & 511;
    int kc = i / 5, gate = i - kc * 5;
    *(bf16x8*)&wl[off8] =
        *(const bf16x8*)(Wcf + (((kc * 16 + g) * 5 + gate) << 9) + inner);
  }
  __syncthreads();
  int lane = tid & 63, wave = tid >> 6;
  int m = lane & 15, quad = lane >> 4;
  int col = g * 16 + m;
  float bb0 = bias5[col], bb1 = bias5[256 + col], bb2 = bias5[512 + col];
  float bb3 = bias5[768 + col], bb4 = bias5[1024 + col];
  const bf16x8 zz = {0, 0, 0, 0, 0, 0, 0, 0};

  const float* cs = cs0;
  const unsigned short* hs = hs0;
  int par = 0, fi = 0;
  for (int B = 512; B >= 1; B >>= 1) {
    int tiles = (B + 15) >> 4;
    float* dc = par ? cP1 : cP0;
    unsigned short* dh = par ? hP1 : hP0;
    int t = rp * 4 + wave;
    if (t < tiles) {
      f32x4 a0 = {0.f, 0.f, 0.f, 0.f}, a1 = a0, a2 = a0, a3 = a0, a4 = a0;
      int ra = t * 16 + m;
      bool okA = (ra < B);
      const unsigned short* ar = hs + ra * 512 + quad * 8;
#pragma unroll
      for (int kh = 0; kh < 2; kh++) {
        bf16x8 av[8];
#pragma unroll
        for (int j = 0; j < 8; j++)
          av[j] = okA ? *(const bf16x8*)(ar + (kh * 8 + j) * 32) : zz;
#pragma unroll
        for (int j = 0; j < 8; j++) {
          int kc = kh * 8 + j;
          const unsigned short* wp = wl + kc * 5 * 512 + lane * 8;
          a0 = __builtin_amdgcn_mfma_f32_16x16x32_bf16(av[j], *(const bf16x8*)(wp), a0, 0, 0, 0);
          a1 = __builtin_amdgcn_mfma_f32_16x16x32_bf16(av[j], *(const bf16x8*)(wp + 512), a1, 0, 0, 0);
          a2 = __builtin_amdgcn_mfma_f32_16x16x32_bf16(av[j], *(const bf16x8*)(wp + 1024), a2, 0, 0, 0);
          a3 = __builtin_amdgcn_mfma_f32_16x16x32_bf16(av[j], *(const bf16x8*)(wp + 1536), a3, 0, 0, 0);
          a4 = __builtin_amdgcn_mfma_f32_16x16x32_bf16(av[j], *(const bf16x8*)(wp + 2048), a4, 0, 0, 0);
        }
      }
#pragma unroll
      for (int reg = 0; reg < 4; reg++) {
        int row = t * 16 + quad * 4 + reg;
        if (row >= B) continue;
        float u = tanhf(a0[reg] + bb0);
        float ig = sigf(a1[reg] + bb1);
        float lf = sigf(a2[reg] + bb2);
        float rf = sigf(a3[reg] + bb3);
        float o = sigf(a4[reg] + bb4);
        float lc = cs[(2 * row) * MEM + col];
        float rc = cs[(2 * row + 1) * MEM + col];
        float c = ig * u + lf * lc + rf * rc;
        float h = o * tanhf(c);
        if (B == 1) {
          outv[col] = c;
          outv[256 + col] = h;
        } else {
          dc[row * MEM + col] = c;
          dh[row * MEM + col] = f2b(h);
        }
      }
    }
    if (B == 1) break;
    // ---- lean flag barrier (level fi) ----
    __syncthreads();  // drains vmcnt: all block writes complete to L2
    if (tid == 0) {
      if (rp * 4 < tiles)  // this block produced data this level
        __hip_atomic_fetch_add(&flags[fi], 1u, __ATOMIC_RELEASE,
                               __HIP_MEMORY_SCOPE_AGENT);
      int arp = (tiles + 3) >> 2;
      if (arp > 8) arp = 8;
      unsigned expect = 16u * (unsigned)arp;
      while (__hip_atomic_load(&flags[fi], __ATOMIC_RELAXED,
                               __HIP_MEMORY_SCOPE_AGENT) < expect)
        __builtin_amdgcn_s_sleep(2);
      (void)__hip_atomic_load(&flags[fi], __ATOMIC_ACQUIRE,
                              __HIP_MEMORY_SCOPE_AGENT);
    }
    __syncthreads();
    cs = dc;
    hs = dh;
    par ^= 1;
    fi++;
  }
}

extern "C" void kernel_launch(void* const* d_in, const int* in_sizes, int n_in,
                              void* d_out, int out_size, void* d_ws, size_t ws_size,
                              hipStream_t stream) {
  const float* embs = (const float*)d_in[0];
  const float* Wx = (const float*)d_in[1];
  const float* bx = (const float*)d_in[2];
  const float* Wl = (const float*)d_in[3];
  const float* Wr = (const float*)d_in[4];
  const float* emb_table = (const float*)d_in[5];
  float* out = (float*)d_out;

  // Workspace layout (~25 MB)
  float* ws = (float*)d_ws;
  float* cA = ws;                               // 8192*256 f32
  float* cB = cA + 8192 * 256;                  // 4096*256 f32
  float* bias5 = cB + 4096 * 256;               // 1280 f32
  unsigned short* hA = (unsigned short*)(bias5 + 1280);  // 8192*256 bf16
  unsigned short* hB = hA + 8192 * 256;                  // 4096*256 bf16
  unsigned short* Wcf = hB + 4096 * 256;                 // 1280*512
  unsigned short* Wxf = Wcf + 1280 * 512;                // 480*512
  unsigned short* eb = Wxf + 480 * 512;                  // 8192*320
  unsigned int* flags = (unsigned int*)(eb + 8192 * 320);  // 16 u32

  // 1) Prep1: eb + Wxf + zero flags (1400 blocks)
  k_prep1<<<NB_EB + NB_WXF, 256, 0, stream>>>(embs, Wx, eb, Wxf, flags);

  // 2) Leaf (+ Wcf shuffle + bias5 overlapped) -> cA, hA
  k_leaf_fused<<<NB_LEAF + NB_WCF + 5, 256, 0, stream>>>(
      eb, Wxf, bx, Wx, Wl, Wr, emb_table + (in_sizes[5] - 300),
      Wcf, bias5, cA, hA);

  // 3) B=4096: RT=2 row-affine compose: (hA,cA) -> (cB,hB)
  k_compose_rt2<<<512, 256, 0, stream>>>(hA, cA, Wcf, bias5, cB, hB, 4096);

  // 4) B=2048: ksplit: (hB,cB) -> (cA,hA)
  k_compose_ksplit<<<dim3(64, 16), 256, 0, stream>>>(
      hB, cB, Wcf, bias5, cA, hA, 2048);

  // 5) B=1024: ksplit: (hA,cA) -> (cB,hB)
  k_compose_ksplit<<<dim3(32, 16), 256, 0, stream>>>(
      hA, cA, Wcf, bias5, cB, hB, 1024);

  // 6) Fused tail B=512..1: input (cB,hB); ping-pong cA/hA <-> cB/hB; -> out
  k_tail<<<128, 256, 0, stream>>>(cB, hB, cA, hA, cB, hB, Wcf, bias5, out, flags);
}